// Round 9
// baseline (199.507 us; speedup 1.0000x reference)
//
#include <hip/hip_runtime.h>
#include <math.h>

// Problem constants (fixed by setup_inputs)
#define BB 8
#define TT 8
#define NN 196
#define DD 768
#define HH 12
#define HD 64
#define TN (TT * NN)   // 1568
#define MM (BB * TN)   // 12544
#define D3 (3 * DD)    // 2304

typedef _Float16 f16;
typedef _Float16 f16x8 __attribute__((ext_vector_type(8)));
typedef _Float16 f16x4 __attribute__((ext_vector_type(4)));
typedef float f32x4 __attribute__((ext_vector_type(4)));
typedef unsigned int u32;

// async global->LDS, 16B per lane; LDS dest must be wave-uniform base + lane*16
#define GLDS16(gp, lp)                                                        \
  __builtin_amdgcn_global_load_lds(                                           \
      (const __attribute__((address_space(1))) u32*)(gp),                     \
      (__attribute__((address_space(3))) u32*)(lp), 16, 0, 0)

#define MFMA16(a, b, c) __builtin_amdgcn_mfma_f32_16x16x32_f16(a, b, c, 0, 0, 0)
#define SBAR() __builtin_amdgcn_s_barrier()
#define SCHED() __builtin_amdgcn_sched_barrier(0)
#define PBAR()  do { SCHED(); SBAR(); SCHED(); } while (0)

// ---------------------------------------------------------------------------
// 256x256 8-phase fp16 GEMM template, K = 768 fixed (both GEMMs share it).
// STRUCTURALLY FROZEN (R6 analysis): per-K-tile LDS traffic = 192KB/CU
// (A-slices x4 waves, B-slices x2) vs 640 MFMA-cyc -> LDS-BW-bound at ~85%
// of the 69 TB/s ceiling; MfmaUtil 31% is the ceiling for this decomposition.
// R5's 32x32 shape switch fired bank conflicts (4.06M) — do not revisit
// without a hardware-verified swizzle.
// C = A[12544][768] @ Bt[NTN*256][768]^T
// MODE 1 (qkv): fp16 out scattered to qkv tile layout; NTN=9 (441 blocks)
// MODE 0 (proj): fp32 out token-major + bias;          NTN=3 (147 blocks)
// ---------------------------------------------------------------------------
#define GK DD    // 768
#define GNT 12   // K tiles of 64

template <int MI0, int NJ0>
__device__ __forceinline__ void quad(f32x4 (&acc)[8][4],
                                     const f16x8 (&af)[4][2],
                                     const f16x8 (&bf)[2][2]) {
  __builtin_amdgcn_s_setprio(1);
#pragma unroll
  for (int i = 0; i < 4; i++)
#pragma unroll
    for (int j = 0; j < 2; j++) {
      acc[MI0 + i][NJ0 + j] = MFMA16(af[i][0], bf[j][0], acc[MI0 + i][NJ0 + j]);
      acc[MI0 + i][NJ0 + j] = MFMA16(af[i][1], bf[j][1], acc[MI0 + i][NJ0 + j]);
    }
  __builtin_amdgcn_s_setprio(0);
}

template <int MODE, int NTN>
__global__ __launch_bounds__(512, 2) void gemm256(
    const f16* __restrict__ A, const f16* __restrict__ Bt,
    f16* __restrict__ C16, float* __restrict__ C32,
    const float* __restrict__ bias) {
  __shared__ f16 As[2 * 256 * 64];
  __shared__ f16 Bs[2 * 256 * 64];

  // bijective XCD swizzle over 49*NTN blocks
  const int nwg = 49 * NTN;
  const int orig = blockIdx.x;
  const int xcd = orig & 7;
  const int inner = orig >> 3;
  const int qq = nwg >> 3;
  const int rr = nwg & 7;
  const int swzid =
      ((xcd < rr) ? xcd * (qq + 1) : rr * (qq + 1) + (xcd - rr) * qq) + inner;
  const int bm = (swzid / NTN) * 256;
  const int bn = (swzid % NTN) * 256;

  const int tid = threadIdx.x;
  const int lane = tid & 63;
  const int wave = tid >> 6;      // 0..7
  const int wy = wave >> 2;       // 0..1  (M half)
  const int wx = wave & 3;        // 0..3  (N quarter)
  const int m = lane & 15;
  const int q = lane >> 4;

  // --- staging: thread handles phys chunks {tid, tid+512} of each 128x64
  // half-tile; row = chunk>>3 (+64), phys slot = chunk&7,
  // logical chunk = slot ^ (row&7) pre-applied to the GLOBAL address.
  const int sr = tid >> 3;                 // 0..63
  const int sc = (tid & 7) ^ (sr & 7);
  const f16* gA = A + (size_t)(bm + sr) * GK + sc * 8;
  const f16* gB = Bt + (size_t)(bn + sr) * GK + sc * 8;
  f16* lA = &As[tid * 8];
  f16* lB = &Bs[tid * 8];

#define STAGE_A(db, h, tile)                                   \
  do {                                                         \
    const f16* _s = gA + (size_t)(h) * 128 * GK + (tile) * 64; \
    f16* _d = lA + (db) * 16384 + (h) * 8192;                  \
    GLDS16(_s, _d);                                            \
    GLDS16(_s + 64 * GK, _d + 4096);                           \
  } while (0)
#define STAGE_B(db, h, tile)                                   \
  do {                                                         \
    const f16* _s = gB + (size_t)(h) * 128 * GK + (tile) * 64; \
    f16* _d = lB + (db) * 16384 + (h) * 8192;                  \
    GLDS16(_s, _d);                                            \
    GLDS16(_s + 64 * GK, _d + 4096);                           \
  } while (0)

  // --- fragment read addressing (row&7 == m&7 for every fragment row)
  const int sw = m & 7;
  const int c0 = (q ^ sw) * 8;
  const int c1 = ((q + 4) ^ sw) * 8;
  const f16* rA = &As[(wy * 128 + m) * 64];
  const f16* rB = &Bs[(wx * 64 + m) * 64];

  // --- prologue: A(0),B(0) then B(1); allow B(1) (4 loads) outstanding
  STAGE_A(0, 0, 0);
  STAGE_A(0, 1, 0);
  STAGE_B(0, 0, 0);
  STAGE_B(0, 1, 0);
  STAGE_B(1, 0, 1);
  STAGE_B(1, 1, 1);

  f32x4 acc[8][4];
#pragma unroll
  for (int i = 0; i < 8; i++)
#pragma unroll
    for (int j = 0; j < 4; j++) acc[i][j] = (f32x4)0.0f;

  SCHED();
  asm volatile("s_waitcnt vmcnt(4)" ::: "memory");
  SCHED();
  SBAR();
  SCHED();

#pragma unroll 2
  for (int t = 0; t < GNT; ++t) {
    const int db = t & 1;
    const f16* pA = rA + db * 16384;
    const f16* pB = rB + db * 16384;
    const int tA = (t + 1 < GNT) ? t + 1 : GNT - 1;
    const int tB = (t + 2 < GNT) ? t + 2 : GNT - 1;

    f16x8 af[4][2], bf0[2][2], bf1[2][2];

    // ---- Phase 1: af(mi0-3) + bf(ni0-1); stage A-h0(t+1)
#pragma unroll
    for (int i = 0; i < 4; i++) {
      af[i][0] = *(const f16x8*)(pA + i * 1024 + c0);
      af[i][1] = *(const f16x8*)(pA + i * 1024 + c1);
    }
#pragma unroll
    for (int j = 0; j < 2; j++) {
      bf0[j][0] = *(const f16x8*)(pB + j * 1024 + c0);
      bf0[j][1] = *(const f16x8*)(pB + j * 1024 + c1);
    }
    STAGE_A(db ^ 1, 0, tA);
    PBAR();
    quad<0, 0>(acc, af, bf0);
    PBAR();

    // ---- Phase 2: bf(ni2-3); stage A-h1(t+1)
#pragma unroll
    for (int j = 0; j < 2; j++) {
      bf1[j][0] = *(const f16x8*)(pB + (2 + j) * 1024 + c0);
      bf1[j][1] = *(const f16x8*)(pB + (2 + j) * 1024 + c1);
    }
    STAGE_A(db ^ 1, 1, tA);
    PBAR();
    quad<0, 2>(acc, af, bf1);
    PBAR();

    // ---- Phase 3: af(mi4-7); stage B-h0(t+2) into CURRENT buf (B reads done)
#pragma unroll
    for (int i = 0; i < 4; i++) {
      af[i][0] = *(const f16x8*)(pA + (4 + i) * 1024 + c0);
      af[i][1] = *(const f16x8*)(pA + (4 + i) * 1024 + c1);
    }
    STAGE_B(db, 0, tB);
    PBAR();
    quad<4, 2>(acc, af, bf1);
    PBAR();

    // ---- Phase 4: stage B-h1(t+2); counted vmcnt (A(t+1)+older must land,
    //      B(t+2) pair stays in flight)
    STAGE_B(db, 1, tB);
    SCHED();
    asm volatile("s_waitcnt vmcnt(4)" ::: "memory");
    PBAR();
    quad<4, 0>(acc, af, bf0);
    PBAR();
  }

  // ---- epilogue
  const int col0 = bn + wx * 64;
  if constexpr (MODE == 1) {
    // qkv scatter to attention tile layout
#pragma unroll
    for (int mi = 0; mi < 8; mi++) {
      const int row0 = bm + wy * 128 + mi * 16 + q * 4;
#pragma unroll
      for (int r = 0; r < 4; r++) {
        const int token = row0 + r;
        const int f = token / NN;
        const int n = token - f * NN;
        f16* fb = C16 + ((size_t)f * (HH * 3)) * (NN * 64) + n * 64;
#pragma unroll
        for (int ni = 0; ni < 4; ni++) {
          const int col = col0 + ni * 16 + m;
          const int qt = col / DD;
          const int rem = col - qt * DD;
          const int hh = rem >> 6;
          const int d = rem & 63;
          fb[(size_t)(hh * 3 + qt) * (NN * 64) + d] = (f16)acc[mi][ni][r];
        }
      }
    }
  } else {
    // proj: token-major fp32 + bias
#pragma unroll
    for (int mi = 0; mi < 8; mi++) {
      const int row0 = bm + wy * 128 + mi * 16 + q * 4;
#pragma unroll
      for (int ni = 0; ni < 4; ni++) {
        const int col = col0 + ni * 16 + m;
        const float bv = bias[col];
#pragma unroll
        for (int r = 0; r < 4; r++)
          C32[(size_t)(row0 + r) * (NTN * 256) + col] = acc[mi][ni][r] + bv;
      }
    }
  }
#undef STAGE_A
#undef STAGE_B
}

// ---------------------------------------------------------------------------
// prep: fused input conversion + both weight transposes (one launch).
// ---------------------------------------------------------------------------
#define CONV_BLOCKS 2048
#define TQ_BLOCKS ((D3 / 32) * (DD / 32))  // 72*24 = 1728
#define TP_BLOCKS ((DD / 32) * (DD / 32))  // 24*24 = 576
#define PREP_BLOCKS (CONV_BLOCKS + TQ_BLOCKS + TP_BLOCKS)  // 4352

__global__ __launch_bounds__(256) void prep(
    const float* __restrict__ x, f16* __restrict__ xh,
    const float* __restrict__ w_qkv, f16* __restrict__ wqkvT,
    const float* __restrict__ w_proj, f16* __restrict__ wprojT) {
  __shared__ float tileS[32][33];
  const int bid = blockIdx.x;
  if (bid < CONV_BLOCKS) {
    const int n4 = MM * DD / 4;
    int i = bid * 256 + threadIdx.x;
    const int stride = CONV_BLOCKS * 256;
    for (; i < n4; i += stride) {
      float4 f = ((const float4*)x)[i];
      f16x4 h;
      h[0] = (f16)f.x;
      h[1] = (f16)f.y;
      h[2] = (f16)f.z;
      h[3] = (f16)f.w;
      ((f16x4*)xh)[i] = h;
    }
    return;
  }
  const float* W;
  f16* Wt;
  int Ncol, id;
  if (bid < CONV_BLOCKS + TQ_BLOCKS) {
    id = bid - CONV_BLOCKS;
    W = w_qkv;
    Wt = wqkvT;
    Ncol = D3;
  } else {
    id = bid - CONV_BLOCKS - TQ_BLOCKS;
    W = w_proj;
    Wt = wprojT;
    Ncol = DD;
  }
  const int nx = Ncol / 32;
  const int n0 = (id % nx) * 32;
  const int k0 = (id / nx) * 32;
  const int tx = threadIdx.x & 31, ty = threadIdx.x >> 5;
#pragma unroll
  for (int i = 0; i < 4; i++)
    tileS[ty + i * 8][tx] = W[(size_t)(k0 + ty + i * 8) * Ncol + n0 + tx];
  __syncthreads();
#pragma unroll
  for (int i = 0; i < 4; i++)
    Wt[(size_t)(n0 + ty + i * 8) * DD + k0 + tx] = (f16)tileS[tx][ty + i * 8];
}

// ---------------------------------------------------------------------------
// MFMA attention per (b,h,t), 512 threads (8 waves).
// R9: grid reverted to 768 (R8 split regressed: staging duplication > makespan
// gain => attn is staging-bound). V staging restructured: was 28 scalar 2B
// global loads/thread (the R8-indicted phase); now 7 vector 8B coalesced
// loads + LDS-side scalar transpose writes. vmean computed from VS rows
// (pad cols zeroed -> full-stride sum exact). Math bit-identical.
// ---------------------------------------------------------------------------
#define VSTR 232

__global__ __launch_bounds__(512, 4) void attn_mfma(
    const f16* __restrict__ qkv, f16* __restrict__ out) {
  __shared__ f16 KS[196 * 64];
  __shared__ f16 VS[64 * VSTR];
  __shared__ __align__(16) f16 PS[8 * 16 * 40];
  __shared__ float vmean[64];

  const int bi = blockIdx.x;  // b*H*T + h*T + t
  const int t = bi % TT;
  const int h = (bi / TT) % HH;
  const int b = bi / (TT * HH);
  const int frame = b * TT + t;
  const int tok0 = frame * NN;

  const f16* Qb = qkv + (size_t)(frame * HH + h) * 3 * NN * 64;
  const f16* Kb = Qb + NN * 64;
  const f16* Vb = Qb + 2 * NN * 64;

  const int tid = threadIdx.x;
  const int lane = tid & 63;
  const int wave = tid >> 6;  // 0..7
  const int m = lane & 15;
  const int q = lane >> 4;

  // ---- stage K via global_load_lds (swizzled source), 1568 chunks ----
#pragma unroll
  for (int it = 0; it < 3; it++) {
    int chunk = tid + it * 512;
    int row = chunk >> 3, pc = chunk & 7;
    int c = pc ^ (row & 7);
    GLDS16(Kb + row * 64 + c * 8, &KS[chunk * 8]);
  }
  if (tid < 32) {  // remainder 32 chunks (rows 192..195), regular path
    int chunk = 1536 + tid;
    int row = chunk >> 3, pc = chunk & 7;
    int c = pc ^ (row & 7);
    *(f16x8*)&KS[chunk * 8] = *(const f16x8*)(Kb + row * 64 + c * 8);
  }

  // ---- zero VS pad cols [196,232) ----
  for (int idx = tid; idx < 64 * 9; idx += 512) {
    int d = idx / 9, c = idx % 9;
    *(f16x4*)&VS[d * VSTR + 196 + c * 4] = (f16x4){0, 0, 0, 0};
  }

  // ---- stage V^T: vector 8B coalesced loads + LDS transpose writes ----
  // thread (quad=tid&15, krow=tid>>4): loads V[k][quad*4..+3] (16 lanes x 8B
  // = 128B contiguous per k-row), scatters 4 scalar writes into VS^T.
  {
    const int quad = tid & 15;
    const int krow = tid >> 4;  // 0..31
#pragma unroll
    for (int it = 0; it < 7; it++) {
      const int k = krow + it * 32;  // 0..223
      if (k < NN) {
        f16x4 v4 = *(const f16x4*)(Vb + k * 64 + quad * 4);
#pragma unroll
        for (int j = 0; j < 4; j++) VS[(quad * 4 + j) * VSTR + k] = v4[j];
      }
    }
  }
  __syncthreads();  // drains K DMA + pad zeros + V writes

  // ---- vmean from VS rows (pad cols are zero -> full-stride sum exact) ----
  if (tid < 64) {
    float s = 0.0f;
#pragma unroll
    for (int c = 0; c < VSTR; c += 8) {
      f16x8 v = *(const f16x8*)&VS[tid * VSTR + c];
#pragma unroll
      for (int j = 0; j < 8; j++) s += (float)v[j];
    }
    vmean[tid] = s * (1.0f / (float)NN);
  }
  __syncthreads();

  f16* PSw = &PS[wave * 640];

  for (int qt = wave; qt < 13; qt += 8) {
    const int q0 = qt * 16;
    int qrow = q0 + m;
    if (qrow > NN - 1) qrow = NN - 1;  // clamp padded queries (write-guarded)
    const f16* qbase = Qb + qrow * 64;
    f16x8 aq0 = *(const f16x8*)(qbase + q * 8);
    f16x8 aq1 = *(const f16x8*)(qbase + 32 + q * 8);

    f32x4 o0 = (f32x4)0.0f, o1 = (f32x4)0.0f, o2 = (f32x4)0.0f,
          o3 = (f32x4)0.0f;
    float l[4] = {0.0f, 0.0f, 0.0f, 0.0f};

    for (int ch = 0; ch < 7; ch++) {
      const int keyA = ch * 32 + m;
      const int keyB = keyA + 16;
      const int kA = keyA > 195 ? 195 : keyA;
      const int kB = keyB > 195 ? 195 : keyB;
      const int swA = kA & 7, swB = kB & 7;
      f16x8 b00 = *(const f16x8*)&KS[kA * 64 + ((q ^ swA) * 8)];
      f16x8 b01 = *(const f16x8*)&KS[kA * 64 + (((q + 4) ^ swA) * 8)];
      f16x8 b10 = *(const f16x8*)&KS[kB * 64 + ((q ^ swB) * 8)];
      f16x8 b11 = *(const f16x8*)&KS[kB * 64 + (((q + 4) ^ swB) * 8)];
      f32x4 z = (f32x4)0.0f;
      __builtin_amdgcn_s_setprio(1);
      f32x4 s0 = MFMA16(aq0, b00, z);
      s0 = MFMA16(aq1, b01, s0);
      f32x4 s1 = MFMA16(aq0, b10, z);
      s1 = MFMA16(aq1, b11, s1);
      __builtin_amdgcn_s_setprio(0);

      const bool v0 = keyA < NN;
      const bool v1 = keyB < NN;
#pragma unroll
      for (int r = 0; r < 4; r++) {
        float p0 = v0 ? __expf(s0[r] * 0.125f) : 0.0f;
        float p1 = v1 ? __expf(s1[r] * 0.125f) : 0.0f;
        l[r] += p0 + p1;
        PSw[(q * 4 + r) * 40 + m] = (f16)p0;
        PSw[(q * 4 + r) * 40 + 16 + m] = (f16)p1;
      }
      f16x8 pa = *(const f16x8*)&PSw[m * 40 + q * 8];
      f16x8 bv0 = *(const f16x8*)&VS[(0 * 16 + m) * VSTR + ch * 32 + q * 8];
      f16x8 bv1 = *(const f16x8*)&VS[(1 * 16 + m) * VSTR + ch * 32 + q * 8];
      f16x8 bv2 = *(const f16x8*)&VS[(2 * 16 + m) * VSTR + ch * 32 + q * 8];
      f16x8 bv3 = *(const f16x8*)&VS[(3 * 16 + m) * VSTR + ch * 32 + q * 8];
      __builtin_amdgcn_s_setprio(1);
      o0 = MFMA16(pa, bv0, o0);
      o1 = MFMA16(pa, bv1, o1);
      o2 = MFMA16(pa, bv2, o2);
      o3 = MFMA16(pa, bv3, o3);
      __builtin_amdgcn_s_setprio(0);
    }

#pragma unroll
    for (int r = 0; r < 4; r++) {
      float s = l[r];
      s += __shfl_xor(s, 1);
      s += __shfl_xor(s, 2);
      s += __shfl_xor(s, 4);
      s += __shfl_xor(s, 8);
      l[r] = 1.0f / s;
    }

#pragma unroll
    for (int r = 0; r < 4; r++) {
      const int query = q0 + q * 4 + r;
      if (query < NN) {
        f16* orow = out + (size_t)(tok0 + query) * DD + h * HD;
        orow[m] = (f16)(o0[r] * l[r] + vmean[m]);
        orow[16 + m] = (f16)(o1[r] * l[r] + vmean[16 + m]);
        orow[32 + m] = (f16)(o2[r] * l[r] + vmean[32 + m]);
        orow[48 + m] = (f16)(o3[r] * l[r] + vmean[48 + m]);
      }
    }
  }
}

// ---------------------------------------------------------------------------
extern "C" void kernel_launch(void* const* d_in, const int* in_sizes, int n_in,
                              void* d_out, int out_size, void* d_ws,
                              size_t ws_size, hipStream_t stream) {
  (void)in_sizes;
  (void)n_in;
  (void)out_size;
  (void)ws_size;
  const float* x      = (const float*)d_in[0];
  const float* w_qkv  = (const float*)d_in[3];
  const float* w_proj = (const float*)d_in[4];
  const float* b_proj = (const float*)d_in[5];
  float* out = (float*)d_out;

  // workspace: qkvh (fp16 MM*D3, tile layout) | xh (fp16 MM*DD, reused for
  //            attn out) | wqkvT | wprojT   (~82 MB total)
  char* ws = (char*)d_ws;
  f16* qkvh = (f16*)ws;
  f16* xh = (f16*)(ws + (size_t)MM * D3 * 2);
  f16* wqkvT = xh + (size_t)MM * DD;
  f16* wprojT = wqkvT + (size_t)D3 * DD;

  // 0) fused prep: x->fp16, w_qkv^T->fp16, w_proj^T->fp16 (one launch)
  prep<<<PREP_BLOCKS, 256, 0, stream>>>(x, xh, w_qkv, wqkvT, w_proj, wprojT);
  // 1) qkv (fp16, attention tile layout) = x @ w_qkv  -- 256^2 8-phase
  gemm256<1, 9><<<dim3(49 * 9), 512, 0, stream>>>(xh, wqkvT, qkvh, nullptr,
                                                  nullptr);
  // 2) MFMA attention + temporal mean -> fp16 token-major (overwrites xh)
  attn_mfma<<<BB * HH * TT, 512, 0, stream>>>(qkvh, xh);
  // 3) out = attn @ w_proj + b_proj (fp32 out) -- 256^2 8-phase, single round
  gemm256<0, 3><<<dim3(49 * 3), 512, 0, stream>>>(xh, wprojT, nullptr, out,
                                                  b_proj);
}

// Round 10
// 195.503 us; speedup vs baseline: 1.0205x; 1.0205x over previous
//
#include <hip/hip_runtime.h>
#include <math.h>

// Problem constants (fixed by setup_inputs)
#define BB 8
#define TT 8
#define NN 196
#define DD 768
#define HH 12
#define HD 64
#define TN (TT * NN)   // 1568
#define MM (BB * TN)   // 12544
#define D3 (3 * DD)    // 2304

typedef _Float16 f16;
typedef _Float16 f16x8 __attribute__((ext_vector_type(8)));
typedef _Float16 f16x4 __attribute__((ext_vector_type(4)));
typedef float f32x4 __attribute__((ext_vector_type(4)));
typedef unsigned int u32;

// async global->LDS, 16B per lane; LDS dest must be wave-uniform base + lane*16
#define GLDS16(gp, lp)                                                        \
  __builtin_amdgcn_global_load_lds(                                           \
      (const __attribute__((address_space(1))) u32*)(gp),                     \
      (__attribute__((address_space(3))) u32*)(lp), 16, 0, 0)

#define MFMA16(a, b, c) __builtin_amdgcn_mfma_f32_16x16x32_f16(a, b, c, 0, 0, 0)
#define SBAR() __builtin_amdgcn_s_barrier()
#define SCHED() __builtin_amdgcn_sched_barrier(0)
#define PBAR()  do { SCHED(); SBAR(); SCHED(); } while (0)

// ---------------------------------------------------------------------------
// 256x256 8-phase fp16 GEMM template, K = 768 fixed (both GEMMs share it).
// STRUCTURALLY FROZEN (R6 analysis): per-K-tile LDS traffic = 192KB/CU
// (A-slices x4 waves, B-slices x2) vs 640 MFMA-cyc -> LDS-BW-bound at ~85%
// of the 69 TB/s ceiling; MfmaUtil 31% is the ceiling for this decomposition.
// R5's 32x32 shape switch fired bank conflicts (4.06M) — do not revisit
// without a hardware-verified swizzle.
// C = A[12544][768] @ Bt[NTN*256][768]^T
// MODE 1 (qkv): fp16 out scattered to qkv tile layout; NTN=9 (441 blocks)
// MODE 0 (proj): fp32 out token-major + bias;          NTN=3 (147 blocks)
// ---------------------------------------------------------------------------
#define GK DD    // 768
#define GNT 12   // K tiles of 64

template <int MI0, int NJ0>
__device__ __forceinline__ void quad(f32x4 (&acc)[8][4],
                                     const f16x8 (&af)[4][2],
                                     const f16x8 (&bf)[2][2]) {
  __builtin_amdgcn_s_setprio(1);
#pragma unroll
  for (int i = 0; i < 4; i++)
#pragma unroll
    for (int j = 0; j < 2; j++) {
      acc[MI0 + i][NJ0 + j] = MFMA16(af[i][0], bf[j][0], acc[MI0 + i][NJ0 + j]);
      acc[MI0 + i][NJ0 + j] = MFMA16(af[i][1], bf[j][1], acc[MI0 + i][NJ0 + j]);
    }
  __builtin_amdgcn_s_setprio(0);
}

template <int MODE, int NTN>
__global__ __launch_bounds__(512, 2) void gemm256(
    const f16* __restrict__ A, const f16* __restrict__ Bt,
    f16* __restrict__ C16, float* __restrict__ C32,
    const float* __restrict__ bias) {
  __shared__ f16 As[2 * 256 * 64];
  __shared__ f16 Bs[2 * 256 * 64];

  // bijective XCD swizzle over 49*NTN blocks
  const int nwg = 49 * NTN;
  const int orig = blockIdx.x;
  const int xcd = orig & 7;
  const int inner = orig >> 3;
  const int qq = nwg >> 3;
  const int rr = nwg & 7;
  const int swzid =
      ((xcd < rr) ? xcd * (qq + 1) : rr * (qq + 1) + (xcd - rr) * qq) + inner;
  const int bm = (swzid / NTN) * 256;
  const int bn = (swzid % NTN) * 256;

  const int tid = threadIdx.x;
  const int lane = tid & 63;
  const int wave = tid >> 6;      // 0..7
  const int wy = wave >> 2;       // 0..1  (M half)
  const int wx = wave & 3;        // 0..3  (N quarter)
  const int m = lane & 15;
  const int q = lane >> 4;

  // --- staging: thread handles phys chunks {tid, tid+512} of each 128x64
  // half-tile; row = chunk>>3 (+64), phys slot = chunk&7,
  // logical chunk = slot ^ (row&7) pre-applied to the GLOBAL address.
  const int sr = tid >> 3;                 // 0..63
  const int sc = (tid & 7) ^ (sr & 7);
  const f16* gA = A + (size_t)(bm + sr) * GK + sc * 8;
  const f16* gB = Bt + (size_t)(bn + sr) * GK + sc * 8;
  f16* lA = &As[tid * 8];
  f16* lB = &Bs[tid * 8];

#define STAGE_A(db, h, tile)                                   \
  do {                                                         \
    const f16* _s = gA + (size_t)(h) * 128 * GK + (tile) * 64; \
    f16* _d = lA + (db) * 16384 + (h) * 8192;                  \
    GLDS16(_s, _d);                                            \
    GLDS16(_s + 64 * GK, _d + 4096);                           \
  } while (0)
#define STAGE_B(db, h, tile)                                   \
  do {                                                         \
    const f16* _s = gB + (size_t)(h) * 128 * GK + (tile) * 64; \
    f16* _d = lB + (db) * 16384 + (h) * 8192;                  \
    GLDS16(_s, _d);                                            \
    GLDS16(_s + 64 * GK, _d + 4096);                           \
  } while (0)

  // --- fragment read addressing (row&7 == m&7 for every fragment row)
  const int sw = m & 7;
  const int c0 = (q ^ sw) * 8;
  const int c1 = ((q + 4) ^ sw) * 8;
  const f16* rA = &As[(wy * 128 + m) * 64];
  const f16* rB = &Bs[(wx * 64 + m) * 64];

  // --- prologue: A(0),B(0) then B(1); allow B(1) (4 loads) outstanding
  STAGE_A(0, 0, 0);
  STAGE_A(0, 1, 0);
  STAGE_B(0, 0, 0);
  STAGE_B(0, 1, 0);
  STAGE_B(1, 0, 1);
  STAGE_B(1, 1, 1);

  f32x4 acc[8][4];
#pragma unroll
  for (int i = 0; i < 8; i++)
#pragma unroll
    for (int j = 0; j < 4; j++) acc[i][j] = (f32x4)0.0f;

  SCHED();
  asm volatile("s_waitcnt vmcnt(4)" ::: "memory");
  SCHED();
  SBAR();
  SCHED();

#pragma unroll 2
  for (int t = 0; t < GNT; ++t) {
    const int db = t & 1;
    const f16* pA = rA + db * 16384;
    const f16* pB = rB + db * 16384;
    const int tA = (t + 1 < GNT) ? t + 1 : GNT - 1;
    const int tB = (t + 2 < GNT) ? t + 2 : GNT - 1;

    f16x8 af[4][2], bf0[2][2], bf1[2][2];

    // ---- Phase 1: af(mi0-3) + bf(ni0-1); stage A-h0(t+1)
#pragma unroll
    for (int i = 0; i < 4; i++) {
      af[i][0] = *(const f16x8*)(pA + i * 1024 + c0);
      af[i][1] = *(const f16x8*)(pA + i * 1024 + c1);
    }
#pragma unroll
    for (int j = 0; j < 2; j++) {
      bf0[j][0] = *(const f16x8*)(pB + j * 1024 + c0);
      bf0[j][1] = *(const f16x8*)(pB + j * 1024 + c1);
    }
    STAGE_A(db ^ 1, 0, tA);
    PBAR();
    quad<0, 0>(acc, af, bf0);
    PBAR();

    // ---- Phase 2: bf(ni2-3); stage A-h1(t+1)
#pragma unroll
    for (int j = 0; j < 2; j++) {
      bf1[j][0] = *(const f16x8*)(pB + (2 + j) * 1024 + c0);
      bf1[j][1] = *(const f16x8*)(pB + (2 + j) * 1024 + c1);
    }
    STAGE_A(db ^ 1, 1, tA);
    PBAR();
    quad<0, 2>(acc, af, bf1);
    PBAR();

    // ---- Phase 3: af(mi4-7); stage B-h0(t+2) into CURRENT buf (B reads done)
#pragma unroll
    for (int i = 0; i < 4; i++) {
      af[i][0] = *(const f16x8*)(pA + (4 + i) * 1024 + c0);
      af[i][1] = *(const f16x8*)(pA + (4 + i) * 1024 + c1);
    }
    STAGE_B(db, 0, tB);
    PBAR();
    quad<4, 2>(acc, af, bf1);
    PBAR();

    // ---- Phase 4: stage B-h1(t+2); counted vmcnt (A(t+1)+older must land,
    //      B(t+2) pair stays in flight)
    STAGE_B(db, 1, tB);
    SCHED();
    asm volatile("s_waitcnt vmcnt(4)" ::: "memory");
    PBAR();
    quad<4, 0>(acc, af, bf0);
    PBAR();
  }

  // ---- epilogue
  const int col0 = bn + wx * 64;
  if constexpr (MODE == 1) {
    // qkv scatter to attention tile layout
#pragma unroll
    for (int mi = 0; mi < 8; mi++) {
      const int row0 = bm + wy * 128 + mi * 16 + q * 4;
#pragma unroll
      for (int r = 0; r < 4; r++) {
        const int token = row0 + r;
        const int f = token / NN;
        const int n = token - f * NN;
        f16* fb = C16 + ((size_t)f * (HH * 3)) * (NN * 64) + n * 64;
#pragma unroll
        for (int ni = 0; ni < 4; ni++) {
          const int col = col0 + ni * 16 + m;
          const int qt = col / DD;
          const int rem = col - qt * DD;
          const int hh = rem >> 6;
          const int d = rem & 63;
          fb[(size_t)(hh * 3 + qt) * (NN * 64) + d] = (f16)acc[mi][ni][r];
        }
      }
    }
  } else {
    // proj: token-major fp32 + bias
#pragma unroll
    for (int mi = 0; mi < 8; mi++) {
      const int row0 = bm + wy * 128 + mi * 16 + q * 4;
#pragma unroll
      for (int ni = 0; ni < 4; ni++) {
        const int col = col0 + ni * 16 + m;
        const float bv = bias[col];
#pragma unroll
        for (int r = 0; r < 4; r++)
          C32[(size_t)(row0 + r) * (NTN * 256) + col] = acc[mi][ni][r] + bv;
      }
    }
  }
#undef STAGE_A
#undef STAGE_B
}

// ---------------------------------------------------------------------------
// prep: fused input conversion + both weight transposes (one launch).
// ---------------------------------------------------------------------------
#define CONV_BLOCKS 2048
#define TQ_BLOCKS ((D3 / 32) * (DD / 32))  // 72*24 = 1728
#define TP_BLOCKS ((DD / 32) * (DD / 32))  // 24*24 = 576
#define PREP_BLOCKS (CONV_BLOCKS + TQ_BLOCKS + TP_BLOCKS)  // 4352

__global__ __launch_bounds__(256) void prep(
    const float* __restrict__ x, f16* __restrict__ xh,
    const float* __restrict__ w_qkv, f16* __restrict__ wqkvT,
    const float* __restrict__ w_proj, f16* __restrict__ wprojT) {
  __shared__ float tileS[32][33];
  const int bid = blockIdx.x;
  if (bid < CONV_BLOCKS) {
    const int n4 = MM * DD / 4;
    int i = bid * 256 + threadIdx.x;
    const int stride = CONV_BLOCKS * 256;
    for (; i < n4; i += stride) {
      float4 f = ((const float4*)x)[i];
      f16x4 h;
      h[0] = (f16)f.x;
      h[1] = (f16)f.y;
      h[2] = (f16)f.z;
      h[3] = (f16)f.w;
      ((f16x4*)xh)[i] = h;
    }
    return;
  }
  const float* W;
  f16* Wt;
  int Ncol, id;
  if (bid < CONV_BLOCKS + TQ_BLOCKS) {
    id = bid - CONV_BLOCKS;
    W = w_qkv;
    Wt = wqkvT;
    Ncol = D3;
  } else {
    id = bid - CONV_BLOCKS - TQ_BLOCKS;
    W = w_proj;
    Wt = wprojT;
    Ncol = DD;
  }
  const int nx = Ncol / 32;
  const int n0 = (id % nx) * 32;
  const int k0 = (id / nx) * 32;
  const int tx = threadIdx.x & 31, ty = threadIdx.x >> 5;
#pragma unroll
  for (int i = 0; i < 4; i++)
    tileS[ty + i * 8][tx] = W[(size_t)(k0 + ty + i * 8) * Ncol + n0 + tx];
  __syncthreads();
#pragma unroll
  for (int i = 0; i < 4; i++)
    Wt[(size_t)(n0 + ty + i * 8) * DD + k0 + tx] = (f16)tileS[tx][ty + i * 8];
}

// ---------------------------------------------------------------------------
// MFMA attention per (b,h,t), 512 threads (8 waves).  (R6 configuration —
// measured best. Attn experiment ledger: R7/R8 half-block split +3.4us
// (staging duplication > makespan gain); R9 V-restage +4.4us (introduced
// 8-way LDS write conflicts; the ORIGINAL V staging below is already
// coalesced on the global side — 64 lanes x 2B = 128B/instr — and
// conflict-free on the LDS side). setprio (T5) kept: -0.9us.)
// ---------------------------------------------------------------------------
#define VSTR 232

__global__ __launch_bounds__(512, 4) void attn_mfma(
    const f16* __restrict__ qkv, f16* __restrict__ out) {
  __shared__ f16 KS[196 * 64];
  __shared__ f16 VS[64 * VSTR];
  __shared__ __align__(16) f16 PS[8 * 16 * 40];
  __shared__ float vmean[64];
  float* red = (float*)PS;  // red used strictly before PS (barrier between)

  const int bi = blockIdx.x;  // b*H*T + h*T + t
  const int t = bi % TT;
  const int h = (bi / TT) % HH;
  const int b = bi / (TT * HH);
  const int frame = b * TT + t;
  const int tok0 = frame * NN;

  const f16* Qb = qkv + (size_t)(frame * HH + h) * 3 * NN * 64;
  const f16* Kb = Qb + NN * 64;
  const f16* Vb = Qb + 2 * NN * 64;

  const int tid = threadIdx.x;
  const int lane = tid & 63;
  const int wave = tid >> 6;  // 0..7
  const int m = lane & 15;
  const int q = lane >> 4;

#pragma unroll
  for (int it = 0; it < 3; it++) {
    int chunk = tid + it * 512;
    int row = chunk >> 3, pc = chunk & 7;
    int c = pc ^ (row & 7);
    GLDS16(Kb + row * 64 + c * 8, &KS[chunk * 8]);
  }
  if (tid < 32) {
    int chunk = 1536 + tid;
    int row = chunk >> 3, pc = chunk & 7;
    int c = pc ^ (row & 7);
    *(f16x8*)&KS[chunk * 8] = *(const f16x8*)(Kb + row * 64 + c * 8);
  }

  for (int idx = tid; idx < 64 * 9; idx += 512) {
    int d = idx / 9, c = idx % 9;
    *(f16x4*)&VS[d * VSTR + 196 + c * 4] = (f16x4){0, 0, 0, 0};
  }

  const int vd = tid & 63;
  const int kb = tid >> 6;
  float vpart = 0.0f;
  if (kb < 7) {
#pragma unroll
    for (int it = 0; it < 7; it++) {
      int k0 = kb * 28 + it * 4;
      f16x4 pk;
#pragma unroll
      for (int j = 0; j < 4; j++) {
        f16 v = Vb[(k0 + j) * 64 + vd];
        pk[j] = v;
        vpart += (float)v;
      }
      *(f16x4*)&VS[vd * VSTR + k0] = pk;
    }
  }
  red[tid] = vpart;
  __syncthreads();
  if (tid < 64) {
    float s = 0.0f;
#pragma unroll
    for (int g = 0; g < 8; g++) s += red[tid + 64 * g];
    vmean[tid] = s * (1.0f / (float)NN);
  }
  __syncthreads();

  f16* PSw = &PS[wave * 640];

  for (int qt = wave; qt < 13; qt += 8) {
    const int q0 = qt * 16;
    int qrow = q0 + m;
    if (qrow > NN - 1) qrow = NN - 1;
    const f16* qbase = Qb + qrow * 64;
    f16x8 aq0 = *(const f16x8*)(qbase + q * 8);
    f16x8 aq1 = *(const f16x8*)(qbase + 32 + q * 8);

    f32x4 o0 = (f32x4)0.0f, o1 = (f32x4)0.0f, o2 = (f32x4)0.0f,
          o3 = (f32x4)0.0f;
    float l[4] = {0.0f, 0.0f, 0.0f, 0.0f};

    for (int ch = 0; ch < 7; ch++) {
      const int keyA = ch * 32 + m;
      const int keyB = keyA + 16;
      const int kA = keyA > 195 ? 195 : keyA;
      const int kB = keyB > 195 ? 195 : keyB;
      const int swA = kA & 7, swB = kB & 7;
      f16x8 b00 = *(const f16x8*)&KS[kA * 64 + ((q ^ swA) * 8)];
      f16x8 b01 = *(const f16x8*)&KS[kA * 64 + (((q + 4) ^ swA) * 8)];
      f16x8 b10 = *(const f16x8*)&KS[kB * 64 + ((q ^ swB) * 8)];
      f16x8 b11 = *(const f16x8*)&KS[kB * 64 + (((q + 4) ^ swB) * 8)];
      f32x4 z = (f32x4)0.0f;
      __builtin_amdgcn_s_setprio(1);
      f32x4 s0 = MFMA16(aq0, b00, z);
      s0 = MFMA16(aq1, b01, s0);
      f32x4 s1 = MFMA16(aq0, b10, z);
      s1 = MFMA16(aq1, b11, s1);
      __builtin_amdgcn_s_setprio(0);

      const bool v0 = keyA < NN;
      const bool v1 = keyB < NN;
#pragma unroll
      for (int r = 0; r < 4; r++) {
        float p0 = v0 ? __expf(s0[r] * 0.125f) : 0.0f;
        float p1 = v1 ? __expf(s1[r] * 0.125f) : 0.0f;
        l[r] += p0 + p1;
        PSw[(q * 4 + r) * 40 + m] = (f16)p0;
        PSw[(q * 4 + r) * 40 + 16 + m] = (f16)p1;
      }
      f16x8 pa = *(const f16x8*)&PSw[m * 40 + q * 8];
      f16x8 bv0 = *(const f16x8*)&VS[(0 * 16 + m) * VSTR + ch * 32 + q * 8];
      f16x8 bv1 = *(const f16x8*)&VS[(1 * 16 + m) * VSTR + ch * 32 + q * 8];
      f16x8 bv2 = *(const f16x8*)&VS[(2 * 16 + m) * VSTR + ch * 32 + q * 8];
      f16x8 bv3 = *(const f16x8*)&VS[(3 * 16 + m) * VSTR + ch * 32 + q * 8];
      __builtin_amdgcn_s_setprio(1);
      o0 = MFMA16(pa, bv0, o0);
      o1 = MFMA16(pa, bv1, o1);
      o2 = MFMA16(pa, bv2, o2);
      o3 = MFMA16(pa, bv3, o3);
      __builtin_amdgcn_s_setprio(0);
    }

#pragma unroll
    for (int r = 0; r < 4; r++) {
      float s = l[r];
      s += __shfl_xor(s, 1);
      s += __shfl_xor(s, 2);
      s += __shfl_xor(s, 4);
      s += __shfl_xor(s, 8);
      l[r] = 1.0f / s;
    }

#pragma unroll
    for (int r = 0; r < 4; r++) {
      const int query = q0 + q * 4 + r;
      if (query < NN) {
        f16* orow = out + (size_t)(tok0 + query) * DD + h * HD;
        orow[m] = (f16)(o0[r] * l[r] + vmean[m]);
        orow[16 + m] = (f16)(o1[r] * l[r] + vmean[16 + m]);
        orow[32 + m] = (f16)(o2[r] * l[r] + vmean[32 + m]);
        orow[48 + m] = (f16)(o3[r] * l[r] + vmean[48 + m]);
      }
    }
  }
}

// ---------------------------------------------------------------------------
extern "C" void kernel_launch(void* const* d_in, const int* in_sizes, int n_in,
                              void* d_out, int out_size, void* d_ws,
                              size_t ws_size, hipStream_t stream) {
  (void)in_sizes;
  (void)n_in;
  (void)out_size;
  (void)ws_size;
  const float* x      = (const float*)d_in[0];
  const float* w_qkv  = (const float*)d_in[3];
  const float* w_proj = (const float*)d_in[4];
  const float* b_proj = (const float*)d_in[5];
  float* out = (float*)d_out;

  // workspace: qkvh (fp16 MM*D3, tile layout) | xh (fp16 MM*DD, reused for
  //            attn out) | wqkvT | wprojT   (~82 MB total)
  char* ws = (char*)d_ws;
  f16* qkvh = (f16*)ws;
  f16* xh = (f16*)(ws + (size_t)MM * D3 * 2);
  f16* wqkvT = xh + (size_t)MM * DD;
  f16* wprojT = wqkvT + (size_t)D3 * DD;

  // 0) fused prep: x->fp16, w_qkv^T->fp16, w_proj^T->fp16 (one launch)
  prep<<<PREP_BLOCKS, 256, 0, stream>>>(x, xh, w_qkv, wqkvT, w_proj, wprojT);
  // 1) qkv (fp16, attention tile layout) = x @ w_qkv  -- 256^2 8-phase
  gemm256<1, 9><<<dim3(49 * 9), 512, 0, stream>>>(xh, wqkvT, qkvh, nullptr,
                                                  nullptr);
  // 2) MFMA attention + temporal mean -> fp16 token-major (overwrites xh)
  attn_mfma<<<BB * HH * TT, 512, 0, stream>>>(qkvh, xh);
  // 3) out = attn @ w_proj + b_proj (fp32 out) -- 256^2 8-phase, single round
  gemm256<0, 3><<<dim3(49 * 3), 512, 0, stream>>>(xh, wprojT, nullptr, out,
                                                  b_proj);
}

// Round 11
// 194.830 us; speedup vs baseline: 1.0240x; 1.0035x over previous
//
#include <hip/hip_runtime.h>
#include <math.h>

// Problem constants (fixed by setup_inputs)
#define BB 8
#define TT 8
#define NN 196
#define DD 768
#define HH 12
#define HD 64
#define TN (TT * NN)   // 1568
#define MM (BB * TN)   // 12544
#define D3 (3 * DD)    // 2304

typedef _Float16 f16;
typedef _Float16 f16x8 __attribute__((ext_vector_type(8)));
typedef _Float16 f16x4 __attribute__((ext_vector_type(4)));
typedef float f32x4 __attribute__((ext_vector_type(4)));
typedef unsigned int u32;

// async global->LDS, 16B per lane; LDS dest must be wave-uniform base + lane*16
#define GLDS16(gp, lp)                                                        \
  __builtin_amdgcn_global_load_lds(                                           \
      (const __attribute__((address_space(1))) u32*)(gp),                     \
      (__attribute__((address_space(3))) u32*)(lp), 16, 0, 0)

#define MFMA16(a, b, c) __builtin_amdgcn_mfma_f32_16x16x32_f16(a, b, c, 0, 0, 0)
#define SBAR() __builtin_amdgcn_s_barrier()
#define SCHED() __builtin_amdgcn_sched_barrier(0)
#define PBAR()  do { SCHED(); SBAR(); SCHED(); } while (0)

// ---------------------------------------------------------------------------
// 256x256 8-phase fp16 GEMM template, K = 768 fixed (both GEMMs share it).
// R11 schedule fix: R6's "LDS-BW floor" claim was WRONG (LDS peak is 256
// B/cyc/CU, not 85 -> structural ceiling is ~50-60% MfmaUtil; we measured 31).
// Cycle accounting located a ~300-cyc all-wave stall per K-tile at P4's
// vmcnt(4): it waits A(t+1)-h1 issued only 2 phases (~600 cyc) earlier vs
// ~900 cyc HBM latency. Fix (hazard-neutral):
//   - stage BOTH A(t+1) halves at P1 (region's last reads are 3+ barriers old)
//   - move vmcnt(4) after P4's MFMA quad (same count, strictly later wait,
//     still before the barrier the t+1 reads depend on)
// A-h1 cover: 2 -> 4 phases (~1200 cyc >= 900). Steady-state at P4-end:
// outstanding = B(t+1)x4 + A(t+1)x4 + B(t+2)x4 = 12; vmcnt(4) lands
// B(t+1)+A(t+1), leaves B(t+2) in flight (same invariant as R6).
// R5's 32x32 shape switch fired bank conflicts (4.06M) — do not revisit
// without a hardware-verified swizzle.
// C = A[12544][768] @ Bt[NTN*256][768]^T
// MODE 1 (qkv): fp16 out scattered to qkv tile layout; NTN=9 (441 blocks)
// MODE 0 (proj): fp32 out token-major + bias;          NTN=3 (147 blocks)
// ---------------------------------------------------------------------------
#define GK DD    // 768
#define GNT 12   // K tiles of 64

template <int MI0, int NJ0>
__device__ __forceinline__ void quad(f32x4 (&acc)[8][4],
                                     const f16x8 (&af)[4][2],
                                     const f16x8 (&bf)[2][2]) {
  __builtin_amdgcn_s_setprio(1);
#pragma unroll
  for (int i = 0; i < 4; i++)
#pragma unroll
    for (int j = 0; j < 2; j++) {
      acc[MI0 + i][NJ0 + j] = MFMA16(af[i][0], bf[j][0], acc[MI0 + i][NJ0 + j]);
      acc[MI0 + i][NJ0 + j] = MFMA16(af[i][1], bf[j][1], acc[MI0 + i][NJ0 + j]);
    }
  __builtin_amdgcn_s_setprio(0);
}

template <int MODE, int NTN>
__global__ __launch_bounds__(512, 2) void gemm256(
    const f16* __restrict__ A, const f16* __restrict__ Bt,
    f16* __restrict__ C16, float* __restrict__ C32,
    const float* __restrict__ bias) {
  __shared__ f16 As[2 * 256 * 64];
  __shared__ f16 Bs[2 * 256 * 64];

  // bijective XCD swizzle over 49*NTN blocks
  const int nwg = 49 * NTN;
  const int orig = blockIdx.x;
  const int xcd = orig & 7;
  const int inner = orig >> 3;
  const int qq = nwg >> 3;
  const int rr = nwg & 7;
  const int swzid =
      ((xcd < rr) ? xcd * (qq + 1) : rr * (qq + 1) + (xcd - rr) * qq) + inner;
  const int bm = (swzid / NTN) * 256;
  const int bn = (swzid % NTN) * 256;

  const int tid = threadIdx.x;
  const int lane = tid & 63;
  const int wave = tid >> 6;      // 0..7
  const int wy = wave >> 2;       // 0..1  (M half)
  const int wx = wave & 3;        // 0..3  (N quarter)
  const int m = lane & 15;
  const int q = lane >> 4;

  // --- staging: thread handles phys chunks {tid, tid+512} of each 128x64
  // half-tile; row = chunk>>3 (+64), phys slot = chunk&7,
  // logical chunk = slot ^ (row&7) pre-applied to the GLOBAL address.
  const int sr = tid >> 3;                 // 0..63
  const int sc = (tid & 7) ^ (sr & 7);
  const f16* gA = A + (size_t)(bm + sr) * GK + sc * 8;
  const f16* gB = Bt + (size_t)(bn + sr) * GK + sc * 8;
  f16* lA = &As[tid * 8];
  f16* lB = &Bs[tid * 8];

#define STAGE_A(db, h, tile)                                   \
  do {                                                         \
    const f16* _s = gA + (size_t)(h) * 128 * GK + (tile) * 64; \
    f16* _d = lA + (db) * 16384 + (h) * 8192;                  \
    GLDS16(_s, _d);                                            \
    GLDS16(_s + 64 * GK, _d + 4096);                           \
  } while (0)
#define STAGE_B(db, h, tile)                                   \
  do {                                                         \
    const f16* _s = gB + (size_t)(h) * 128 * GK + (tile) * 64; \
    f16* _d = lB + (db) * 16384 + (h) * 8192;                  \
    GLDS16(_s, _d);                                            \
    GLDS16(_s + 64 * GK, _d + 4096);                           \
  } while (0)

  // --- fragment read addressing (row&7 == m&7 for every fragment row)
  const int sw = m & 7;
  const int c0 = (q ^ sw) * 8;
  const int c1 = ((q + 4) ^ sw) * 8;
  const f16* rA = &As[(wy * 128 + m) * 64];
  const f16* rB = &Bs[(wx * 64 + m) * 64];

  // --- prologue: A(0),B(0) then B(1); allow B(1) (4 loads) outstanding
  STAGE_A(0, 0, 0);
  STAGE_A(0, 1, 0);
  STAGE_B(0, 0, 0);
  STAGE_B(0, 1, 0);
  STAGE_B(1, 0, 1);
  STAGE_B(1, 1, 1);

  f32x4 acc[8][4];
#pragma unroll
  for (int i = 0; i < 8; i++)
#pragma unroll
    for (int j = 0; j < 4; j++) acc[i][j] = (f32x4)0.0f;

  SCHED();
  asm volatile("s_waitcnt vmcnt(4)" ::: "memory");
  SCHED();
  SBAR();
  SCHED();

#pragma unroll 2
  for (int t = 0; t < GNT; ++t) {
    const int db = t & 1;
    const f16* pA = rA + db * 16384;
    const f16* pB = rB + db * 16384;
    const int tA = (t + 1 < GNT) ? t + 1 : GNT - 1;
    const int tB = (t + 2 < GNT) ? t + 2 : GNT - 1;

    f16x8 af[4][2], bf0[2][2], bf1[2][2];

    // ---- Phase 1: af(mi0-3) + bf(ni0-1); stage BOTH A(t+1) halves ->buf^1
    //      (4-phase cover to the P4-end wait)
#pragma unroll
    for (int i = 0; i < 4; i++) {
      af[i][0] = *(const f16x8*)(pA + i * 1024 + c0);
      af[i][1] = *(const f16x8*)(pA + i * 1024 + c1);
    }
#pragma unroll
    for (int j = 0; j < 2; j++) {
      bf0[j][0] = *(const f16x8*)(pB + j * 1024 + c0);
      bf0[j][1] = *(const f16x8*)(pB + j * 1024 + c1);
    }
    STAGE_A(db ^ 1, 0, tA);
    STAGE_A(db ^ 1, 1, tA);
    PBAR();
    quad<0, 0>(acc, af, bf0);
    PBAR();

    // ---- Phase 2: bf(ni2-3); no staging
#pragma unroll
    for (int j = 0; j < 2; j++) {
      bf1[j][0] = *(const f16x8*)(pB + (2 + j) * 1024 + c0);
      bf1[j][1] = *(const f16x8*)(pB + (2 + j) * 1024 + c1);
    }
    PBAR();
    quad<0, 2>(acc, af, bf1);
    PBAR();

    // ---- Phase 3: af(mi4-7); stage B-h0(t+2) into CURRENT buf (B reads done
    //      by P2's closing barrier)
#pragma unroll
    for (int i = 0; i < 4; i++) {
      af[i][0] = *(const f16x8*)(pA + (4 + i) * 1024 + c0);
      af[i][1] = *(const f16x8*)(pA + (4 + i) * 1024 + c1);
    }
    STAGE_B(db, 0, tB);
    PBAR();
    quad<4, 2>(acc, af, bf1);
    PBAR();

    // ---- Phase 4: stage B-h1(t+2); MFMA first, THEN counted vmcnt (one
    //      extra phase of latency cover; A(t+1)+B(t+1) must land, B(t+2)
    //      pair stays in flight across the tile boundary)
    STAGE_B(db, 1, tB);
    PBAR();
    quad<4, 0>(acc, af, bf0);
    SCHED();
    asm volatile("s_waitcnt vmcnt(4)" ::: "memory");
    PBAR();
  }

  // ---- epilogue
  const int col0 = bn + wx * 64;
  if constexpr (MODE == 1) {
    // qkv scatter to attention tile layout
#pragma unroll
    for (int mi = 0; mi < 8; mi++) {
      const int row0 = bm + wy * 128 + mi * 16 + q * 4;
#pragma unroll
      for (int r = 0; r < 4; r++) {
        const int token = row0 + r;
        const int f = token / NN;
        const int n = token - f * NN;
        f16* fb = C16 + ((size_t)f * (HH * 3)) * (NN * 64) + n * 64;
#pragma unroll
        for (int ni = 0; ni < 4; ni++) {
          const int col = col0 + ni * 16 + m;
          const int qt = col / DD;
          const int rem = col - qt * DD;
          const int hh = rem >> 6;
          const int d = rem & 63;
          fb[(size_t)(hh * 3 + qt) * (NN * 64) + d] = (f16)acc[mi][ni][r];
        }
      }
    }
  } else {
    // proj: token-major fp32 + bias
#pragma unroll
    for (int mi = 0; mi < 8; mi++) {
      const int row0 = bm + wy * 128 + mi * 16 + q * 4;
#pragma unroll
      for (int ni = 0; ni < 4; ni++) {
        const int col = col0 + ni * 16 + m;
        const float bv = bias[col];
#pragma unroll
        for (int r = 0; r < 4; r++)
          C32[(size_t)(row0 + r) * (NTN * 256) + col] = acc[mi][ni][r] + bv;
      }
    }
  }
#undef STAGE_A
#undef STAGE_B
}

// ---------------------------------------------------------------------------
// prep: fused input conversion + both weight transposes (one launch).
// ---------------------------------------------------------------------------
#define CONV_BLOCKS 2048
#define TQ_BLOCKS ((D3 / 32) * (DD / 32))  // 72*24 = 1728
#define TP_BLOCKS ((DD / 32) * (DD / 32))  // 24*24 = 576
#define PREP_BLOCKS (CONV_BLOCKS + TQ_BLOCKS + TP_BLOCKS)  // 4352

__global__ __launch_bounds__(256) void prep(
    const float* __restrict__ x, f16* __restrict__ xh,
    const float* __restrict__ w_qkv, f16* __restrict__ wqkvT,
    const float* __restrict__ w_proj, f16* __restrict__ wprojT) {
  __shared__ float tileS[32][33];
  const int bid = blockIdx.x;
  if (bid < CONV_BLOCKS) {
    const int n4 = MM * DD / 4;
    int i = bid * 256 + threadIdx.x;
    const int stride = CONV_BLOCKS * 256;
    for (; i < n4; i += stride) {
      float4 f = ((const float4*)x)[i];
      f16x4 h;
      h[0] = (f16)f.x;
      h[1] = (f16)f.y;
      h[2] = (f16)f.z;
      h[3] = (f16)f.w;
      ((f16x4*)xh)[i] = h;
    }
    return;
  }
  const float* W;
  f16* Wt;
  int Ncol, id;
  if (bid < CONV_BLOCKS + TQ_BLOCKS) {
    id = bid - CONV_BLOCKS;
    W = w_qkv;
    Wt = wqkvT;
    Ncol = D3;
  } else {
    id = bid - CONV_BLOCKS - TQ_BLOCKS;
    W = w_proj;
    Wt = wprojT;
    Ncol = DD;
  }
  const int nx = Ncol / 32;
  const int n0 = (id % nx) * 32;
  const int k0 = (id / nx) * 32;
  const int tx = threadIdx.x & 31, ty = threadIdx.x >> 5;
#pragma unroll
  for (int i = 0; i < 4; i++)
    tileS[ty + i * 8][tx] = W[(size_t)(k0 + ty + i * 8) * Ncol + n0 + tx];
  __syncthreads();
#pragma unroll
  for (int i = 0; i < 4; i++)
    Wt[(size_t)(n0 + ty + i * 8) * DD + k0 + tx] = (f16)tileS[tx][ty + i * 8];
}

// ---------------------------------------------------------------------------
// MFMA attention per (b,h,t), 512 threads (8 waves).  (R6 configuration —
// measured best. Attn experiment ledger: R7/R8 half-block split +3.4us
// (staging duplication > makespan gain); R9 V-restage +4.4us (introduced
// 8-way LDS write conflicts; the ORIGINAL V staging below is already
// coalesced on the global side — 64 lanes x 2B = 128B/instr — and
// conflict-free on the LDS side). setprio (T5) kept: -0.9us.)
// ---------------------------------------------------------------------------
#define VSTR 232

__global__ __launch_bounds__(512, 4) void attn_mfma(
    const f16* __restrict__ qkv, f16* __restrict__ out) {
  __shared__ f16 KS[196 * 64];
  __shared__ f16 VS[64 * VSTR];
  __shared__ __align__(16) f16 PS[8 * 16 * 40];
  __shared__ float vmean[64];
  float* red = (float*)PS;  // red used strictly before PS (barrier between)

  const int bi = blockIdx.x;  // b*H*T + h*T + t
  const int t = bi % TT;
  const int h = (bi / TT) % HH;
  const int b = bi / (TT * HH);
  const int frame = b * TT + t;
  const int tok0 = frame * NN;

  const f16* Qb = qkv + (size_t)(frame * HH + h) * 3 * NN * 64;
  const f16* Kb = Qb + NN * 64;
  const f16* Vb = Qb + 2 * NN * 64;

  const int tid = threadIdx.x;
  const int lane = tid & 63;
  const int wave = tid >> 6;  // 0..7
  const int m = lane & 15;
  const int q = lane >> 4;

#pragma unroll
  for (int it = 0; it < 3; it++) {
    int chunk = tid + it * 512;
    int row = chunk >> 3, pc = chunk & 7;
    int c = pc ^ (row & 7);
    GLDS16(Kb + row * 64 + c * 8, &KS[chunk * 8]);
  }
  if (tid < 32) {
    int chunk = 1536 + tid;
    int row = chunk >> 3, pc = chunk & 7;
    int c = pc ^ (row & 7);
    *(f16x8*)&KS[chunk * 8] = *(const f16x8*)(Kb + row * 64 + c * 8);
  }

  for (int idx = tid; idx < 64 * 9; idx += 512) {
    int d = idx / 9, c = idx % 9;
    *(f16x4*)&VS[d * VSTR + 196 + c * 4] = (f16x4){0, 0, 0, 0};
  }

  const int vd = tid & 63;
  const int kb = tid >> 6;
  float vpart = 0.0f;
  if (kb < 7) {
#pragma unroll
    for (int it = 0; it < 7; it++) {
      int k0 = kb * 28 + it * 4;
      f16x4 pk;
#pragma unroll
      for (int j = 0; j < 4; j++) {
        f16 v = Vb[(k0 + j) * 64 + vd];
        pk[j] = v;
        vpart += (float)v;
      }
      *(f16x4*)&VS[vd * VSTR + k0] = pk;
    }
  }
  red[tid] = vpart;
  __syncthreads();
  if (tid < 64) {
    float s = 0.0f;
#pragma unroll
    for (int g = 0; g < 8; g++) s += red[tid + 64 * g];
    vmean[tid] = s * (1.0f / (float)NN);
  }
  __syncthreads();

  f16* PSw = &PS[wave * 640];

  for (int qt = wave; qt < 13; qt += 8) {
    const int q0 = qt * 16;
    int qrow = q0 + m;
    if (qrow > NN - 1) qrow = NN - 1;
    const f16* qbase = Qb + qrow * 64;
    f16x8 aq0 = *(const f16x8*)(qbase + q * 8);
    f16x8 aq1 = *(const f16x8*)(qbase + 32 + q * 8);

    f32x4 o0 = (f32x4)0.0f, o1 = (f32x4)0.0f, o2 = (f32x4)0.0f,
          o3 = (f32x4)0.0f;
    float l[4] = {0.0f, 0.0f, 0.0f, 0.0f};

    for (int ch = 0; ch < 7; ch++) {
      const int keyA = ch * 32 + m;
      const int keyB = keyA + 16;
      const int kA = keyA > 195 ? 195 : keyA;
      const int kB = keyB > 195 ? 195 : keyB;
      const int swA = kA & 7, swB = kB & 7;
      f16x8 b00 = *(const f16x8*)&KS[kA * 64 + ((q ^ swA) * 8)];
      f16x8 b01 = *(const f16x8*)&KS[kA * 64 + (((q + 4) ^ swA) * 8)];
      f16x8 b10 = *(const f16x8*)&KS[kB * 64 + ((q ^ swB) * 8)];
      f16x8 b11 = *(const f16x8*)&KS[kB * 64 + (((q + 4) ^ swB) * 8)];
      f32x4 z = (f32x4)0.0f;
      __builtin_amdgcn_s_setprio(1);
      f32x4 s0 = MFMA16(aq0, b00, z);
      s0 = MFMA16(aq1, b01, s0);
      f32x4 s1 = MFMA16(aq0, b10, z);
      s1 = MFMA16(aq1, b11, s1);
      __builtin_amdgcn_s_setprio(0);

      const bool v0 = keyA < NN;
      const bool v1 = keyB < NN;
#pragma unroll
      for (int r = 0; r < 4; r++) {
        float p0 = v0 ? __expf(s0[r] * 0.125f) : 0.0f;
        float p1 = v1 ? __expf(s1[r] * 0.125f) : 0.0f;
        l[r] += p0 + p1;
        PSw[(q * 4 + r) * 40 + m] = (f16)p0;
        PSw[(q * 4 + r) * 40 + 16 + m] = (f16)p1;
      }
      f16x8 pa = *(const f16x8*)&PSw[m * 40 + q * 8];
      f16x8 bv0 = *(const f16x8*)&VS[(0 * 16 + m) * VSTR + ch * 32 + q * 8];
      f16x8 bv1 = *(const f16x8*)&VS[(1 * 16 + m) * VSTR + ch * 32 + q * 8];
      f16x8 bv2 = *(const f16x8*)&VS[(2 * 16 + m) * VSTR + ch * 32 + q * 8];
      f16x8 bv3 = *(const f16x8*)&VS[(3 * 16 + m) * VSTR + ch * 32 + q * 8];
      __builtin_amdgcn_s_setprio(1);
      o0 = MFMA16(pa, bv0, o0);
      o1 = MFMA16(pa, bv1, o1);
      o2 = MFMA16(pa, bv2, o2);
      o3 = MFMA16(pa, bv3, o3);
      __builtin_amdgcn_s_setprio(0);
    }

#pragma unroll
    for (int r = 0; r < 4; r++) {
      float s = l[r];
      s += __shfl_xor(s, 1);
      s += __shfl_xor(s, 2);
      s += __shfl_xor(s, 4);
      s += __shfl_xor(s, 8);
      l[r] = 1.0f / s;
    }

#pragma unroll
    for (int r = 0; r < 4; r++) {
      const int query = q0 + q * 4 + r;
      if (query < NN) {
        f16* orow = out + (size_t)(tok0 + query) * DD + h * HD;
        orow[m] = (f16)(o0[r] * l[r] + vmean[m]);
        orow[16 + m] = (f16)(o1[r] * l[r] + vmean[16 + m]);
        orow[32 + m] = (f16)(o2[r] * l[r] + vmean[32 + m]);
        orow[48 + m] = (f16)(o3[r] * l[r] + vmean[48 + m]);
      }
    }
  }
}

// ---------------------------------------------------------------------------
extern "C" void kernel_launch(void* const* d_in, const int* in_sizes, int n_in,
                              void* d_out, int out_size, void* d_ws,
                              size_t ws_size, hipStream_t stream) {
  (void)in_sizes;
  (void)n_in;
  (void)out_size;
  (void)ws_size;
  const float* x      = (const float*)d_in[0];
  const float* w_qkv  = (const float*)d_in[3];
  const float* w_proj = (const float*)d_in[4];
  const float* b_proj = (const float*)d_in[5];
  float* out = (float*)d_out;

  // workspace: qkvh (fp16 MM*D3, tile layout) | xh (fp16 MM*DD, reused for
  //            attn out) | wqkvT | wprojT   (~82 MB total)
  char* ws = (char*)d_ws;
  f16* qkvh = (f16*)ws;
  f16* xh = (f16*)(ws + (size_t)MM * D3 * 2);
  f16* wqkvT = xh + (size_t)MM * DD;
  f16* wprojT = wqkvT + (size_t)D3 * DD;

  // 0) fused prep: x->fp16, w_qkv^T->fp16, w_proj^T->fp16 (one launch)
  prep<<<PREP_BLOCKS, 256, 0, stream>>>(x, xh, w_qkv, wqkvT, w_proj, wprojT);
  // 1) qkv (fp16, attention tile layout) = x @ w_qkv  -- 256^2 8-phase
  gemm256<1, 9><<<dim3(49 * 9), 512, 0, stream>>>(xh, wqkvT, qkvh, nullptr,
                                                  nullptr);
  // 2) MFMA attention + temporal mean -> fp16 token-major (overwrites xh)
  attn_mfma<<<BB * HH * TT, 512, 0, stream>>>(qkvh, xh);
  // 3) out = attn @ w_proj + b_proj (fp32 out) -- 256^2 8-phase, single round
  gemm256<0, 3><<<dim3(49 * 3), 512, 0, stream>>>(xh, wprojT, nullptr, out,
                                                  b_proj);
}